// Round 17
// baseline (4233.001 us; speedup 1.0000x reference)
//
#include <hip/hip_runtime.h>

// ---------------- problem constants ----------------
#define Bn 32
#define Tn 64
#define Pn 196
#define ENCD 2048
#define DECD 512
#define XDIM 2304
#define NWG 256

typedef unsigned short u16;
typedef __attribute__((ext_vector_type(8))) short bf16x8;
typedef __attribute__((ext_vector_type(4))) float f32x4;

#define MF(a,b,c) __builtin_amdgcn_mfma_f32_16x16x32_bf16(a,b,c,0,0,0)

static __device__ __forceinline__ u16 f2bf(float f){
  unsigned int u = __float_as_uint(f);
  unsigned int r = u + 0x7FFFu + ((u >> 16) & 1u);
  return (u16)(r >> 16);
}
static __device__ __forceinline__ float bf2f(u16 u){
  return __uint_as_float(((unsigned int)u) << 16);
}

// agent-scope (L2-bypassing, L3-coherent) helpers — proven in round 4
static __device__ __forceinline__ void cstore_u32(unsigned* p, unsigned v){
  __hip_atomic_store(p, v, __ATOMIC_RELAXED, __HIP_MEMORY_SCOPE_AGENT);
}
static __device__ __forceinline__ unsigned cload_u32(const unsigned* p){
  return __hip_atomic_load((unsigned*)p, __ATOMIC_RELAXED, __HIP_MEMORY_SCOPE_AGENT);
}
static __device__ __forceinline__ void cstore_f32(float* p, float v){
  cstore_u32((unsigned*)p, __float_as_uint(v));
}
static __device__ __forceinline__ float cload_f32(const float* p){
  return __uint_as_float(cload_u32((const unsigned*)p));
}
static __device__ __forceinline__ unsigned long long cload_u64(const unsigned long long* p){
  return __hip_atomic_load((unsigned long long*)p, __ATOMIC_RELAXED, __HIP_MEMORY_SCOPE_AGENT);
}
static __device__ __forceinline__ bf16x8 cload_bf8(const u16* p){
  union { unsigned long long q[2]; bf16x8 v; } u;
  u.q[0] = cload_u64((const unsigned long long*)p);
  u.q[1] = cload_u64((const unsigned long long*)(p + 4));
  return u.v;
}

// fence-free grid barrier: relaxed add + relaxed spin. No wbl2 -> L2 stays warm.
// sc1 data stores complete at L3 before the vmcnt(0) implied by __syncthreads,
// so counter visibility implies data visibility.
static __device__ __forceinline__ void gbar(unsigned* cnt, unsigned target){
  __syncthreads();
  if (threadIdx.x == 0){
    __hip_atomic_fetch_add(cnt, 1u, __ATOMIC_RELAXED, __HIP_MEMORY_SCOPE_AGENT);
    while (__hip_atomic_load(cnt, __ATOMIC_RELAXED, __HIP_MEMORY_SCOPE_AGENT) < target)
      __builtin_amdgcn_s_sleep(1);
  }
  asm volatile("" ::: "memory");
  __syncthreads();
}

// ---------------- output offsets (floats) ----------------
#define O_PRED   0
#define O_STOP   4096
#define O_SEQOFF 6144
#define O_LEN    10240
#define O_ALPHA  10272
#define O_SORT   411680

// ---------------- ws: f32/int region (f32 indices) ----------------
#define WS_SORT    0
#define WS_LEN     32
#define WS_C       64       // f32 [32][512]
#define WS_PA      16448    // f32 [32][4608] (also init partials pre-loop)
#define WS_SCP     163904   // f32 [32][4][200] score partials
#define WS_ENCM    215104   // f32 [32][2048]
#define WS_EMB0    280640   // f32 [32][256]
#define WS_BCOMB   288832   // f32 [2048]
#define WS_BAR     290880   // unsigned barrier counter
// ---------------- ws: u16 region ----------------
#define US_H0      800000
#define US_H1      816384
#define US_XA      832768
#define US_EMBBF   898304
#define US_ATT1T   1422592
#define US_ENC     4830464
#define US_WAP     17675520
#define US_WIHE    20067584
#define US_WIH2    20591872
#define US_GEMB    24786176
#define US_PATCH   20591872
#define US_WPEB    26883328
#define US_WEA     27931904

// ============ prep: stable descending sort + barrier zero ============
__global__ void k_prep(const int* __restrict__ caplen, int* __restrict__ ws_sort,
                       int* __restrict__ ws_len, unsigned* __restrict__ bar,
                       float* __restrict__ out){
  __shared__ int len[32];
  int i = threadIdx.x;
  if (i == 0) *bar = 0u;
  if (i < 32) len[i] = caplen[i];
  __syncthreads();
  if (i < 32){
    int li = len[i], r = 0;
    for (int j = 0; j < 32; j++){
      int lj = len[j];
      r += (lj > li) || (lj == li && j < i);
    }
    ws_sort[r] = i;
    ws_len[r]  = li;
    out[O_LEN + r]  = (float)li;
    out[O_SORT + r] = (float)i;
  }
}

// ============ StageA: encbf | encmean | patch | wpeb | wea | seqoff ============
__global__ __launch_bounds__(256) void k_stageA(const float* __restrict__ enc,
    const float* __restrict__ imgs, const int* __restrict__ seq,
    const float* __restrict__ W_pe, const float* __restrict__ Wea,
    const float* __restrict__ seqoff, const int* __restrict__ srt,
    u16* __restrict__ encbf, float* __restrict__ encm, u16* __restrict__ patches,
    u16* __restrict__ wpeb, u16* __restrict__ wead, float* __restrict__ out){
  int blk = blockIdx.x, tid = threadIdx.x;
  if (blk < 6272){
    int m = blk;
    int b = m / 196, p = m - b*196;
    const float* src = enc + ((size_t)srt[b]*196 + p)*ENCD;
    u16* d = encbf + (size_t)m*ENCD;
    int i = tid*8;
    float4 v0 = *(const float4*)(src + i);
    float4 v1 = *(const float4*)(src + i + 4);
    bf16x8 s;
    s[0]=(short)f2bf(v0.x); s[1]=(short)f2bf(v0.y); s[2]=(short)f2bf(v0.z); s[3]=(short)f2bf(v0.w);
    s[4]=(short)f2bf(v1.x); s[5]=(short)f2bf(v1.y); s[6]=(short)f2bf(v1.z); s[7]=(short)f2bf(v1.w);
    *(bf16x8*)(d + i) = s;
  } else if (blk < 6528){
    int r = blk - 6272;
    int b = r >> 3, dc = r & 7;
    int d = dc*256 + tid;
    const float* ep = enc + ((size_t)srt[b]*196)*ENCD + d;
    float s = 0.f;
    #pragma unroll 4
    for (int p = 0; p < Pn; p++) s += ep[(size_t)p*ENCD];
    encm[b*ENCD + d] = s * (1.f/196.f);
  } else if (blk < 8576){
    int r = blk - 6528;
    int b = r>>6, t = r&63;
    int sb = srt[b];
    int x0 = seq[(sb*64+t)*2 + 0], y0 = seq[(sb*64+t)*2 + 1];
    const float* img = imgs + (size_t)sb*3*512*512;
    u16* dst = patches + (size_t)(b*64+t)*3072;
    for (int idx = tid; idx < 3072; idx += 256){
      int c = idx>>10, rem = idx&1023, i = rem>>5, j = rem&31;
      int yy = y0 + i - 24, xx = x0 + j - 24;
      float v = 0.f;
      if ((unsigned)yy < 512u && (unsigned)xx < 512u) v = img[((size_t)c*512 + yy)*512 + xx];
      dst[idx] = f2bf(v);
    }
  } else if (blk < 9344){
    int i = ((blk - 8576)*256 + tid)*4;
    float4 v = *(const float4*)(W_pe + i);
    wpeb[i+0] = f2bf(v.x); wpeb[i+1] = f2bf(v.y);
    wpeb[i+2] = f2bf(v.z); wpeb[i+3] = f2bf(v.w);
  } else if (blk < 9856){
    int r = blk - 9344;
    for (int i = tid; i < 2048; i += 256)
      wead[(size_t)r*2048 + i] = f2bf(Wea[(size_t)r*2048 + i]);
  } else {
    int idx = (blk - 9856)*256 + tid;
    int b = idx >> 7, r = idx & 127;
    out[O_SEQOFF + idx] = seqoff[srt[b]*128 + r];
  }
}

// ============ StageB: embedv3 | att1v4 ============
__global__ __launch_bounds__(256) void k_stageB(const u16* __restrict__ patches,
    const u16* __restrict__ wpeb, const float* __restrict__ b_pe,
    const u16* __restrict__ encbf, const u16* __restrict__ wead,
    const float* __restrict__ bea,
    u16* __restrict__ embbf, float* __restrict__ emb0, u16* __restrict__ att1T){
  __shared__ u16 A[64*138];
  int blk = blockIdx.x, tid = threadIdx.x;
  int wv = tid>>6, lane = tid&63, lr = lane&15, lh = lane>>4;
  if (blk < 128){
    int mb = blk >> 2, nb = blk & 3;
    int m0 = mb*64;
    f32x4 acc[4];
    #pragma unroll
    for (int mt = 0; mt < 4; mt++) acc[mt] = (f32x4){0,0,0,0};
    for (int kc = 0; kc < 24; kc++){
      __syncthreads();
      {
        int row = tid>>2, seg = tid&3;
        const u16* src = patches + (size_t)(m0 + row)*3072 + kc*128 + seg*32;
        #pragma unroll
        for (int i = 0; i < 4; i++)
          *(bf16x8*)&A[row*138 + seg*32 + i*8] = *(const bf16x8*)(src + i*8);
      }
      __syncthreads();
      #pragma unroll
      for (int ki = 0; ki < 4; ki++){
        bf16x8 bv = *(const bf16x8*)&wpeb[(size_t)(nb*64 + wv*16 + lr)*3072 + kc*128 + ki*32 + lh*8];
        #pragma unroll
        for (int mt = 0; mt < 4; mt++){
          bf16x8 av = *(const bf16x8*)&A[(mt*16 + lr)*138 + ki*32 + lh*8];
          acc[mt] = MF(av, bv, acc[mt]);
        }
      }
    }
    int n = nb*64 + wv*16 + lr;
    float bias = b_pe[n];
    #pragma unroll
    for (int mt = 0; mt < 4; mt++){
      #pragma unroll
      for (int r = 0; r < 4; r++){
        int t = mt*16 + lh*4 + r;
        float val = acc[mt][r] + bias;
        embbf[(size_t)(m0 + t)*256 + n] = f2bf(val);
        if (t == 0) emb0[mb*256 + n] = val;
      }
    }
  } else {
    int ab = blk - 128;
    int mb = ab >> 2, nb = ab & 3;
    int m0 = mb*64;
    f32x4 acc[4][2];
    #pragma unroll
    for (int mt = 0; mt < 4; mt++){ acc[mt][0] = (f32x4){0,0,0,0}; acc[mt][1] = (f32x4){0,0,0,0}; }
    for (int kc = 0; kc < 16; kc++){
      __syncthreads();
      {
        int row = tid>>2, seg = tid&3;
        const u16* src = encbf + (size_t)(m0 + row)*2048 + kc*128 + seg*32;
        #pragma unroll
        for (int i = 0; i < 4; i++)
          *(bf16x8*)&A[row*138 + seg*32 + i*8] = *(const bf16x8*)(src + i*8);
      }
      __syncthreads();
      #pragma unroll
      for (int ki = 0; ki < 4; ki++){
        bf16x8 av[4];
        #pragma unroll
        for (int mt = 0; mt < 4; mt++)
          av[mt] = *(const bf16x8*)&A[(mt*16 + lr)*138 + ki*32 + lh*8];
        #pragma unroll
        for (int nt = 0; nt < 2; nt++){
          const u16* wp = wead + (size_t)(nb*128 + wv*32 + nt*16 + lr)*2048 + kc*128 + ki*32 + lh*8;
          bf16x8 bv = *(const bf16x8*)wp;
          #pragma unroll
          for (int mt = 0; mt < 4; mt++) acc[mt][nt] = MF(av[mt], bv, acc[mt][nt]);
        }
      }
    }
    #pragma unroll
    for (int nt = 0; nt < 2; nt++){
      int n = nb*128 + wv*32 + nt*16 + lr;
      float bias = bea[n];
      #pragma unroll
      for (int mt = 0; mt < 4; mt++){
        #pragma unroll
        for (int r = 0; r < 4; r++){
          int m = m0 + mt*16 + lh*4 + r;
          int bb = m / 196, pp = m - bb*196;
          att1T[((size_t)bb*512 + n)*208 + pp] = f2bf(acc[mt][nt][r] + bias);
        }
      }
    }
  }
}

// ============ StageC: W_ih cvt | WAP | bcomb | initv3 ============
__global__ __launch_bounds__(256) void k_stageC(const float* __restrict__ Wih,
    const float* __restrict__ Whh, const float* __restrict__ Wdec,
    const float* __restrict__ Wfb, const float* __restrict__ Wfc,
    const float* __restrict__ Wstop, const float* __restrict__ bih,
    const float* __restrict__ bhh,
    const float* __restrict__ encm, const float* __restrict__ emb0,
    const float* __restrict__ Wh, const float* __restrict__ Wc,
    u16* __restrict__ WIH2, u16* __restrict__ WIHE, u16* __restrict__ WAP,
    float* __restrict__ bcomb, float* __restrict__ part){
  int blk = blockIdx.x, tid = threadIdx.x;
  if (blk < 2048){
    int r = blk, jp = (r & 511)*4 + (r >> 9);
    for (int i = tid; i < 2304; i += 256){
      u16 v = f2bf(Wih[(size_t)r*2304 + i]);
      if (i < 2048) WIH2[(size_t)jp*2048 + i] = v;
      else          WIHE[(size_t)jp*256 + (i - 2048)] = v;
    }
  } else if (blk < 6720){
    int j = blk - 2048;
    const float* src;
    if (j < 512)        src = Wdec + (size_t)j*512;
    else if (j < 2560)  src = Wfb + (size_t)(j-512)*512;
    else if (j < 4608)  src = Whh + (size_t)(j-2560)*512;
    else if (j == 4608) src = Wfc;
    else if (j == 4609) src = Wfc + 512;
    else if (j == 4610) src = Wstop;
    else src = 0;
    for (int i = tid; i < 512; i += 256)
      WAP[(size_t)j*512 + i] = src ? f2bf(src[i]) : (u16)0;
  } else if (blk < 6728){
    int jp = (blk - 6720)*256 + tid;
    int r = (jp & 3)*512 + (jp >> 2);
    bcomb[jp] = bih[r] + bhh[r];
  } else {
    int ib = blk - 6728;
    int kc = ib >> 4, jb = ib & 15;
    int wv = tid>>6, lane = tid&63, lr = lane&15, lh = lane>>4;
    int j = jb*64 + wv*16 + lr;
    const float* wbase = (j < 512) ? (Wh + (size_t)j*XDIM) : (Wc + (size_t)(j-512)*XDIM);
    f32x4 acc0 = {0,0,0,0}, acc1 = {0,0,0,0};
    #pragma unroll 2
    for (int kk = 0; kk < 576; kk += 32){
      int k = kc*576 + kk + lh*8;
      float4 w0 = *(const float4*)(wbase + k);
      float4 w1 = *(const float4*)(wbase + k + 4);
      bf16x8 bv;
      bv[0]=(short)f2bf(w0.x); bv[1]=(short)f2bf(w0.y); bv[2]=(short)f2bf(w0.z); bv[3]=(short)f2bf(w0.w);
      bv[4]=(short)f2bf(w1.x); bv[5]=(short)f2bf(w1.y); bv[6]=(short)f2bf(w1.z); bv[7]=(short)f2bf(w1.w);
      float4 x0, x1, y0, y1;
      if (k < 2048){
        x0 = *(const float4*)(encm + (size_t)lr*2048 + k);
        x1 = *(const float4*)(encm + (size_t)lr*2048 + k + 4);
        y0 = *(const float4*)(encm + (size_t)(16+lr)*2048 + k);
        y1 = *(const float4*)(encm + (size_t)(16+lr)*2048 + k + 4);
      } else {
        int ke = k - 2048;
        x0 = *(const float4*)(emb0 + (size_t)lr*256 + ke);
        x1 = *(const float4*)(emb0 + (size_t)lr*256 + ke + 4);
        y0 = *(const float4*)(emb0 + (size_t)(16+lr)*256 + ke);
        y1 = *(const float4*)(emb0 + (size_t)(16+lr)*256 + ke + 4);
      }
      bf16x8 a0, a1;
      a0[0]=(short)f2bf(x0.x); a0[1]=(short)f2bf(x0.y); a0[2]=(short)f2bf(x0.z); a0[3]=(short)f2bf(x0.w);
      a0[4]=(short)f2bf(x1.x); a0[5]=(short)f2bf(x1.y); a0[6]=(short)f2bf(x1.z); a0[7]=(short)f2bf(x1.w);
      a1[0]=(short)f2bf(y0.x); a1[1]=(short)f2bf(y0.y); a1[2]=(short)f2bf(y0.z); a1[3]=(short)f2bf(y0.w);
      a1[4]=(short)f2bf(y1.x); a1[5]=(short)f2bf(y1.y); a1[6]=(short)f2bf(y1.z); a1[7]=(short)f2bf(y1.w);
      acc0 = MF(a0, bv, acc0);
      acc1 = MF(a1, bv, acc1);
    }
    #pragma unroll
    for (int r = 0; r < 4; ++r){
      int b0 = lh*4 + r, b1 = 16 + b0;
      part[(size_t)(kc*32 + b0)*1024 + j] = acc0[r];
      part[(size_t)(kc*32 + b1)*1024 + j] = acc1[r];
    }
  }
}

// ============ StageD: gemb | initv3r ============
__global__ __launch_bounds__(256) void k_stageD(const u16* __restrict__ embbf,
    const u16* __restrict__ WIHE, const float* __restrict__ part,
    const float* __restrict__ bh, const float* __restrict__ bc,
    u16* __restrict__ gemb, u16* __restrict__ h_bf, float* __restrict__ c){
  __shared__ u16 A[64*266];
  int blk = blockIdx.x, tid = threadIdx.x;
  if (blk < 256){
    int m0 = (blk >> 3)*64, n0 = (blk & 7)*256;
    int wv = tid>>6, lane = tid&63, lr = lane&15, lh = lane>>4;
    {
      int row = tid>>2, seg = tid&3;
      const u16* src = embbf + (size_t)(m0 + row)*256 + seg*64;
      #pragma unroll
      for (int i = 0; i < 8; i++)
        *(bf16x8*)&A[row*266 + seg*64 + i*8] = *(const bf16x8*)(src + i*8);
    }
    __syncthreads();
    f32x4 acc[4][4];
    #pragma unroll
    for (int mt = 0; mt < 4; mt++)
      #pragma unroll
      for (int nt = 0; nt < 4; nt++) acc[mt][nt] = (f32x4){0,0,0,0};
    #pragma unroll
    for (int ki = 0; ki < 8; ki++){
      bf16x8 av[4];
      #pragma unroll
      for (int mt = 0; mt < 4; mt++)
        av[mt] = *(const bf16x8*)&A[(mt*16 + lr)*266 + ki*32 + lh*8];
      #pragma unroll
      for (int nt = 0; nt < 4; nt++){
        bf16x8 bv = *(const bf16x8*)&WIHE[(size_t)(n0 + wv*64 + nt*16 + lr)*256 + ki*32 + lh*8];
        #pragma unroll
        for (int mt = 0; mt < 4; mt++) acc[mt][nt] = MF(av[mt], bv, acc[mt][nt]);
      }
    }
    #pragma unroll
    for (int nt = 0; nt < 4; nt++){
      int n = n0 + wv*64 + nt*16 + lr;
      #pragma unroll
      for (int mt = 0; mt < 4; mt++)
        #pragma unroll
        for (int r = 0; r < 4; r++)
          gemb[(size_t)(m0 + mt*16 + lh*4 + r)*2048 + n] = f2bf(acc[mt][nt][r]);
    }
  } else {
    int idx = (blk - 256)*256 + tid;
    int b = idx >> 10, j = idx & 1023;
    float s = part[(size_t)b*1024 + j] + part[(size_t)(32+b)*1024 + j]
            + part[(size_t)(64+b)*1024 + j] + part[(size_t)(96+b)*1024 + j];
    if (j < 512) h_bf[(size_t)b*512 + j] = f2bf(s + bh[j]);
    else         c[(size_t)b*512 + (j-512)] = s + bc[j-512];
  }
}

// ============ persistent loop: 3 fence-free barriers per step ============
struct LoopP {
  unsigned* bar;
  float* pA; float* scp; const float* c0; const float* bcomb;
  u16* h0; u16* h1; u16* xa;
  const u16* att1T; const u16* enc; const u16* gemb;
  const u16* WAP; const u16* WIH2;
  const float* bdec; const float* wfull; const float* bfull; const float* bfb;
  const float* bfc; const float* bstop;
  const int* len; float* out;
};

__global__ __launch_bounds__(256) void k_loop(LoopP P){
  const int blk = blockIdx.x, tid = threadIdx.x;
  const int wv = tid>>6, lane = tid&63, lr = lane&15, lh = lane>>4;
  __shared__ __align__(16) char SM[33536];
  unsigned bt = 0;
  float creg0 = 0.f, creg1 = 0.f;   // persistent c for P3 blocks

  for (int t = 0; t <= 64; ++t){
    const u16* hc = (t & 1) ? P.h1 : P.h0;
    // ---------------- P1 ----------------
    if (blk < 64 && t < 64){
      // kA-role: pA rows 512..4607
      u16* HL = (u16*)SM;
      for (int i = tid; i < 4096; i += 256){
        unsigned long long v = cload_u64(((const unsigned long long*)hc) + i);
        int row = i >> 7, col = (i & 127)*4;
        *(unsigned long long*)&HL[row*522 + col] = v;
      }
      __syncthreads();
      int j0 = 512 + blk*64 + wv*16;
      f32x4 acc0 = {0,0,0,0}, acc1 = {0,0,0,0};
      #pragma unroll 4
      for (int ki = 0; ki < 16; ++ki){
        bf16x8 bv = *(const bf16x8*)&P.WAP[(size_t)(j0+lr)*512 + ki*32 + lh*8];
        bf16x8 a0 = *(const bf16x8*)&HL[lr*522 + ki*32 + lh*8];
        bf16x8 a1 = *(const bf16x8*)&HL[(16+lr)*522 + ki*32 + lh*8];
        acc0 = MF(a0, bv, acc0);
        acc1 = MF(a1, bv, acc1);
      }
      int j = j0 + lr;
      #pragma unroll
      for (int r = 0; r < 4; ++r){
        cstore_f32(&P.pA[(size_t)(lh*4+r)*4608 + j], acc0[r]);
        cstore_f32(&P.pA[(size_t)(lh*4+r+16)*4608 + j], acc1[r]);
      }
    } else if (blk == 64 && t > 0){
      // preds-role for t-1 (rows 4608..4610 of WAP)
      if (tid < 192){
        int task = tid >> 1, q = tid & 1;
        int b = task / 3, rw = task - b*3;
        const u16* hrow = hc + (size_t)b*512 + q*256;
        const u16* wrow = P.WAP + (size_t)(4608 + rw)*512 + q*256;
        float acc = 0.f;
        #pragma unroll 4
        for (int i = 0; i < 32; ++i){
          bf16x8 hv8 = cload_bf8(hrow + i*8);
          bf16x8 wv8 = *(const bf16x8*)(wrow + i*8);
          #pragma unroll
          for (int e = 0; e < 8; ++e) acc += bf2f((u16)hv8[e]) * bf2f((u16)wv8[e]);
        }
        acc += __shfl_xor(acc, 1);
        if (q == 0){
          int tm1 = t - 1;
          bool mk = tm1 < P.len[b];
          if (rw < 2) P.out[O_PRED + ((size_t)b*64 + tm1)*2 + rw] = mk ? acc + P.bfc[rw] : 0.f;
          else        P.out[O_STOP + (size_t)b*64 + tm1] =
                        mk ? 1.f/(1.f + expf(-(acc + P.bstop[0]))) : 0.f;
        }
      }
    } else if (blk > 64 && blk < 193 && t < 64){
      // kB1-role: 128 blocks, b = kb>>2, ch = kb&3 (128 a's each)
      int kb = blk - 65, b = kb >> 2, ch = kb & 3;
      if (t < P.len[b]){
        u16* hL = (u16*)SM;                       // 512 u16
        float* a2s = (float*)(SM + 1024);         // 128
        float* wfs = a2s + 128;                   // 128
        if (tid < 128)
          ((unsigned long long*)hL)[tid] = cload_u64(((const unsigned long long*)(hc + (size_t)b*512)) + tid);
        if (tid < 128) wfs[tid] = P.wfull[ch*128 + tid];
        __syncthreads();
        {
          int a = tid >> 1, q = tid & 1;
          const u16* wrow = P.WAP + (size_t)(ch*128 + a)*512 + q*256;
          const u16* hrow = hL + q*256;
          float acc = 0.f;
          #pragma unroll 4
          for (int i = 0; i < 32; ++i){
            bf16x8 wv8 = *(const bf16x8*)(wrow + i*8);
            bf16x8 hv8 = *(const bf16x8*)(hrow + i*8);
            #pragma unroll
            for (int e = 0; e < 8; ++e) acc += bf2f((u16)hv8[e]) * bf2f((u16)wv8[e]);
          }
          acc += __shfl_xor(acc, 1);
          if (q == 0) a2s[a] = acc + P.bdec[ch*128 + a];
        }
        __syncthreads();
        int p = tid;
        if (p < 196){
          const u16* col = P.att1T + ((size_t)b*512 + ch*128)*208 + p;
          float acc = 0.f;
          #pragma unroll 8
          for (int a = 0; a < 128; ++a)
            acc += fmaxf(bf2f(col[(size_t)a*208]) + a2s[a], 0.f) * wfs[a];
          cstore_f32(&P.scp[(size_t)(b*4 + ch)*200 + p], acc);
        }
      }
    }
    if (t == 64) break;
    bt += NWG; gbar(P.bar, bt);

    // ---------------- P2: kB2 (all 256 blocks) ----------------
    {
      int b = blk >> 3, dc = blk & 7;
      if (t < P.len[b]){
        float* ev   = (float*)SM;           // 200
        float* redf = ev + 200;             // 4
        float* bcx  = redf + 4;             // 2
        float s = -1e30f;
        if (tid < 196){
          s = P.bfull[0];
          #pragma unroll
          for (int q = 0; q < 4; ++q) s += cload_f32(&P.scp[(size_t)(b*4 + q)*200 + tid]);
        }
        float m = s;
        #pragma unroll
        for (int o = 32; o; o >>= 1) m = fmaxf(m, __shfl_down(m, o));
        if (lane == 0) redf[wv] = m;
        __syncthreads();
        if (tid == 0) bcx[0] = fmaxf(fmaxf(redf[0],redf[1]), fmaxf(redf[2],redf[3]));
        __syncthreads();
        float e = (tid < 196) ? expf(s - bcx[0]) : 0.f;
        if (tid < 200) ev[tid] = (tid < 196) ? e : 0.f;
        float sm = e;
        #pragma unroll
        for (int o = 32; o; o >>= 1) sm += __shfl_down(sm, o);
        __syncthreads();
        if (lane == 0) redf[wv] = sm;
        __syncthreads();
        if (tid == 0) bcx[1] = redf[0]+redf[1]+redf[2]+redf[3];
        __syncthreads();
        float ssum = bcx[1];
        int d = dc*256 + tid;
        const u16* ep = P.enc + (size_t)(b*196)*ENCD + d;
        float q[8];
        #pragma unroll
        for (int j = 0; j < 8; ++j) q[j] = 0.f;
        #pragma unroll 2
        for (int p = 0; p < 192; p += 8){
          #pragma unroll
          for (int j = 0; j < 8; ++j)
            q[j] += ev[p+j]*bf2f(ep[(size_t)(p+j)*ENCD]);
        }
        #pragma unroll
        for (int j = 0; j < 4; ++j)
          q[j] += ev[192+j]*bf2f(ep[(size_t)(192+j)*ENCD]);
        float awe = (((q[0]+q[1])+(q[2]+q[3])) + ((q[4]+q[5])+(q[6]+q[7]))) / ssum;
        float gp = cload_f32(&P.pA[(size_t)b*4608 + 512 + d]) + P.bfb[d];
        float gate = 1.f/(1.f + expf(-gp));
        unsigned hb16 = f2bf(gate * awe);
        unsigned po = (unsigned)__shfl_xor((int)hb16, 1);
        if ((tid & 1) == 0)
          cstore_u32(((unsigned*)P.xa) + (size_t)b*1024 + (d >> 1), hb16 | (po << 16));
        if (dc == 0 && tid < 196) P.out[O_ALPHA + ((size_t)b*64 + t)*196 + tid] = ev[tid]/ssum;
      } else {
        if (dc == 0 && tid < 196) P.out[O_ALPHA + ((size_t)b*64 + t)*196 + tid] = 0.f;
      }
    }
    bt += NWG; gbar(P.bar, bt);

    // ---------------- P3: kC (blocks 0..127), 4 waves ----------------
    if (blk < 128){
      u16* hn = (t & 1) ? P.h0 : P.h1;
      float* red = (float*)SM;   // [4][512]
      int jp0 = blk*16;
      f32x4 acc0 = {0,0,0,0}, acc1 = {0,0,0,0};
      #pragma unroll 4
      for (int ks = 0; ks < 16; ++ks){
        int k = wv*512 + ks*32;
        bf16x8 a0 = cload_bf8(&P.xa[(size_t)lr*2048 + k + lh*8]);
        bf16x8 a1 = cload_bf8(&P.xa[(size_t)(16+lr)*2048 + k + lh*8]);
        bf16x8 bv = *(const bf16x8*)&P.WIH2[(size_t)(jp0+lr)*2048 + k + lh*8];
        acc0 = MF(a0, bv, acc0);
        acc1 = MF(a1, bv, acc1);
      }
      __syncthreads();
      #pragma unroll
      for (int r = 0; r < 4; ++r){
        red[wv*512 + ((lh*4+r) << 4) + lr]    = acc0[r];
        red[wv*512 + ((16+lh*4+r) << 4) + lr] = acc1[r];
      }
      __syncthreads();
      #pragma unroll
      for (int pass = 0; pass < 2; ++pass){
        int idx = pass*256 + tid;
        int b = idx >> 4, jl = idx & 15, e = jl & 3;
        int jp = jp0 + jl, u = jp >> 2;
        float g = red[idx] + red[512+idx] + red[1024+idx] + red[1536+idx];
        g += P.bcomb[jp] + bf2f(P.gemb[((size_t)b*64 + t)*2048 + jp])
           + cload_f32(&P.pA[(size_t)b*4608 + 2560 + e*512 + u]);
        float creg = pass ? creg1 : creg0;
        if (t == 0) creg = P.c0[(size_t)b*512 + u];
        float sv = (e == 2) ? tanhf(g) : 1.f/(1.f + expf(-g));
        float vb = __shfl_xor(sv, 1), vc = __shfl_xor(sv, 2), vd = __shfl_xor(vb, 2);
        float i_s = (e==0)?sv:(e==1)?vb:(e==2)?vc:vd;
        float f_s = (e==1)?sv:(e==0)?vb:(e==3)?vc:vd;
        float g_t = (e==2)?sv:(e==3)?vb:(e==0)?vc:vd;
        float o_s = (e==3)?sv:(e==2)?vb:(e==1)?vc:vd;
        unsigned hp = cload_u32((const unsigned*)(hc + (size_t)b*512 + (u & ~1)));
        float hold = bf2f((u16)((u & 1) ? (hp >> 16) : (hp & 0xFFFF)));
        bool mk = t < P.len[b];
        float cn = mk ? (f_s*creg + i_s*g_t) : creg;
        float hv = mk ? (o_s * tanhf(cn)) : hold;
        if (pass) creg1 = cn; else creg0 = cn;
        unsigned hb = (unsigned)f2bf(hv);
        unsigned pu = (unsigned)__shfl_xor((int)hb, 4);
        if ((idx & 7) == 0)
          cstore_u32((unsigned*)(hn + (size_t)b*512 + u), hb | (pu << 16));
      }
    }
    bt += NWG; gbar(P.bar, bt);
  }
}

// ================= host launcher =================
extern "C" void kernel_launch(void* const* d_in, const int* in_sizes, int n_in,
                              void* d_out, int out_size, void* d_ws, size_t ws_size,
                              hipStream_t stream){
  (void)in_sizes; (void)n_in; (void)out_size; (void)ws_size;
  const float* enc_out   = (const float*)d_in[0];
  const float* imgs      = (const float*)d_in[1];
  const int*   seq       = (const int*)d_in[2];
  const float* seqoff    = (const float*)d_in[3];
  const int*   caplen    = (const int*)d_in[4];
  const float* W_pe      = (const float*)d_in[5];
  const float* b_pe      = (const float*)d_in[6];
  const float* W_enc_att = (const float*)d_in[7];
  const float* b_enc_att = (const float*)d_in[8];
  const float* W_dec_att = (const float*)d_in[9];
  const float* b_dec_att = (const float*)d_in[10];
  const float* w_full    = (const float*)d_in[11];
  const float* b_full    = (const float*)d_in[12];
  const float* W_init_h  = (const float*)d_in[13];
  const float* b_init_h  = (const float*)d_in[14];
  const float* W_init_c  = (const float*)d_in[15];
  const float* b_init_c  = (const float*)d_in[16];
  const float* W_fb      = (const float*)d_in[17];
  const float* b_fb      = (const float*)d_in[18];
  const float* W_ih      = (const float*)d_in[19];
  const float* b_ih      = (const float*)d_in[20];
  const float* W_hh      = (const float*)d_in[21];
  const float* b_hh      = (const float*)d_in[22];
  const float* W_fc      = (const float*)d_in[23];
  const float* b_fc      = (const float*)d_in[24];
  const float* W_stop    = (const float*)d_in[25];
  const float* b_stop    = (const float*)d_in[26];

  float* out = (float*)d_out;
  float* ws  = (float*)d_ws;
  int*   wsi = (int*)d_ws;
  u16*   us  = (u16*)d_ws;

  k_prep<<<1, 64, 0, stream>>>(caplen, wsi + WS_SORT, wsi + WS_LEN,
                               (unsigned*)(ws + WS_BAR), out);
  k_stageA<<<9872, 256, 0, stream>>>(enc_out, imgs, seq, W_pe, W_enc_att, seqoff,
                                     wsi + WS_SORT,
                                     us + US_ENC, ws + WS_ENCM, us + US_PATCH,
                                     us + US_WPEB, us + US_WEA, out);
  k_stageB<<<520, 256, 0, stream>>>(us + US_PATCH, us + US_WPEB, b_pe,
                                    us + US_ENC, us + US_WEA, b_enc_att,
                                    us + US_EMBBF, ws + WS_EMB0, us + US_ATT1T);
  k_stageC<<<6792, 256, 0, stream>>>(W_ih, W_hh, W_dec_att, W_fb, W_fc, W_stop,
                                     b_ih, b_hh,
                                     ws + WS_ENCM, ws + WS_EMB0, W_init_h, W_init_c,
                                     us + US_WIH2, us + US_WIHE, us + US_WAP,
                                     ws + WS_BCOMB, ws + WS_PA);
  k_stageD<<<384, 256, 0, stream>>>(us + US_EMBBF, us + US_WIHE, ws + WS_PA,
                                    b_init_h, b_init_c,
                                    us + US_GEMB, us + US_H0, ws + WS_C);

  LoopP P;
  P.bar = (unsigned*)(ws + WS_BAR);
  P.pA = ws + WS_PA; P.scp = ws + WS_SCP; P.c0 = ws + WS_C; P.bcomb = ws + WS_BCOMB;
  P.h0 = us + US_H0; P.h1 = us + US_H1; P.xa = us + US_XA;
  P.att1T = us + US_ATT1T; P.enc = us + US_ENC; P.gemb = us + US_GEMB;
  P.WAP = us + US_WAP; P.WIH2 = us + US_WIH2;
  P.bdec = b_dec_att; P.wfull = w_full; P.bfull = b_full; P.bfb = b_fb;
  P.bfc = b_fc; P.bstop = b_stop;
  P.len = wsi + WS_LEN; P.out = out;
  void* ka[1] = { (void*)&P };
  hipLaunchCooperativeKernel((const void*)k_loop, dim3(NWG), dim3(256), ka, 0, stream);
}

// Round 18
// 1835.513 us; speedup vs baseline: 2.3062x; 2.3062x over previous
//
#include <hip/hip_runtime.h>

// ---------------- problem constants ----------------
#define Bn 32
#define Tn 64
#define Pn 196
#define ENCD 2048
#define DECD 512
#define XDIM 2304

typedef unsigned short u16;
typedef __attribute__((ext_vector_type(8))) short bf16x8;
typedef __attribute__((ext_vector_type(4))) float f32x4;

#define MF(a,b,c) __builtin_amdgcn_mfma_f32_16x16x32_bf16(a,b,c,0,0,0)

static __device__ __forceinline__ u16 f2bf(float f){
  unsigned int u = __float_as_uint(f);
  unsigned int r = u + 0x7FFFu + ((u >> 16) & 1u);
  return (u16)(r >> 16);
}
static __device__ __forceinline__ float bf2f(u16 u){
  return __uint_as_float(((unsigned int)u) << 16);
}

// ---------------- output offsets (floats) ----------------
#define O_PRED   0
#define O_STOP   4096
#define O_SEQOFF 6144
#define O_LEN    10240
#define O_ALPHA  10272
#define O_SORT   411680

// ---------------- ws: f32/int region (f32 indices) ----------------
#define WS_SORT    0        // int[32]
#define WS_LEN     32       // int[32]
#define WS_C       64       // f32 [32][512]
#define WS_PA      16448    // f32 [32][4608] (also init partials [4][32][1024] pre-loop)
#define WS_SCP     163904   // f32 [32][8][200] score partials
#define WS_ENCM    215104   // f32 [32][2048]
#define WS_EMB0    280640   // f32 [32][256]
#define WS_BCOMB   288832   // f32 [2048]
// ---------------- ws: u16 region (absolute u16 indices from (u16*)d_ws) ----------------
#define US_H0      800000                 // [32][512]
#define US_H1      816384                 // [32][512]
#define US_XA      832768                 // [32][2048]
#define US_EMBBF   898304                 // [32][64][256]
#define US_ATT1T   1422592                // [32][512][208] transposed att1
#define US_ENC     4830464                // [6272][2048] sorted row-major
#define US_WAP     17675520               // [4672][512] Wdec|Wfb|Whh|Wfc(2)|Wstop|pad
#define US_WIHE    20067584               // [2048][256]  jp-interleaved
#define US_WIH2    20591872               // [2048][2048] jp-interleaved (StageC; clobbers PATCH)
#define US_GEMB    24786176               // [32*64][2048] (StageD; clobbers PATCH tail/WPEB/WEA)
#define US_PATCH   20591872               // [2048][3072] ALIAS (StageA write, StageB read)
#define US_WPEB    26883328               // [256][3072] bf16 W_pe (StageA write, StageB read)
#define US_WEA     27931904               // [512][2048] bf16 W_enc_att (StageA write, StageB read)

// ============ prep: stable descending sort ============
__global__ void k_prep(const int* __restrict__ caplen, int* __restrict__ ws_sort,
                       int* __restrict__ ws_len, float* __restrict__ out){
  __shared__ int len[32];
  int i = threadIdx.x;
  if (i < 32) len[i] = caplen[i];
  __syncthreads();
  if (i < 32){
    int li = len[i], r = 0;
    for (int j = 0; j < 32; j++){
      int lj = len[j];
      r += (lj > li) || (lj == li && j < i);
    }
    ws_sort[r] = i;
    ws_len[r]  = li;
    out[O_LEN + r]  = (float)li;
    out[O_SORT + r] = (float)i;
  }
}

// ============ StageA: encbf | encmean(fp32) | patch | wpeb | wea | seqoff ============
__global__ __launch_bounds__(256) void k_stageA(const float* __restrict__ enc,
    const float* __restrict__ imgs, const int* __restrict__ seq,
    const float* __restrict__ W_pe, const float* __restrict__ Wea,
    const float* __restrict__ seqoff, const int* __restrict__ srt,
    u16* __restrict__ encbf, float* __restrict__ encm, u16* __restrict__ patches,
    u16* __restrict__ wpeb, u16* __restrict__ wead, float* __restrict__ out){
  int blk = blockIdx.x, tid = threadIdx.x;
  if (blk < 6272){
    int m = blk;
    int b = m / 196, p = m - b*196;
    const float* src = enc + ((size_t)srt[b]*196 + p)*ENCD;
    u16* d = encbf + (size_t)m*ENCD;
    int i = tid*8;
    float4 v0 = *(const float4*)(src + i);
    float4 v1 = *(const float4*)(src + i + 4);
    bf16x8 s;
    s[0]=(short)f2bf(v0.x); s[1]=(short)f2bf(v0.y); s[2]=(short)f2bf(v0.z); s[3]=(short)f2bf(v0.w);
    s[4]=(short)f2bf(v1.x); s[5]=(short)f2bf(v1.y); s[6]=(short)f2bf(v1.z); s[7]=(short)f2bf(v1.w);
    *(bf16x8*)(d + i) = s;
  } else if (blk < 6528){
    int r = blk - 6272;
    int b = r >> 3, dc = r & 7;
    int d = dc*256 + tid;
    const float* ep = enc + ((size_t)srt[b]*196)*ENCD + d;
    float s = 0.f;
    #pragma unroll 4
    for (int p = 0; p < Pn; p++) s += ep[(size_t)p*ENCD];
    encm[b*ENCD + d] = s * (1.f/196.f);
  } else if (blk < 8576){
    int r = blk - 6528;
    int b = r>>6, t = r&63;
    int sb = srt[b];
    int x0 = seq[(sb*64+t)*2 + 0], y0 = seq[(sb*64+t)*2 + 1];
    const float* img = imgs + (size_t)sb*3*512*512;
    u16* dst = patches + (size_t)(b*64+t)*3072;
    for (int idx = tid; idx < 3072; idx += 256){
      int c = idx>>10, rem = idx&1023, i = rem>>5, j = rem&31;
      int yy = y0 + i - 24, xx = x0 + j - 24;
      float v = 0.f;
      if ((unsigned)yy < 512u && (unsigned)xx < 512u) v = img[((size_t)c*512 + yy)*512 + xx];
      dst[idx] = f2bf(v);
    }
  } else if (blk < 9344){
    int i = ((blk - 8576)*256 + tid)*4;
    float4 v = *(const float4*)(W_pe + i);
    wpeb[i+0] = f2bf(v.x); wpeb[i+1] = f2bf(v.y);
    wpeb[i+2] = f2bf(v.z); wpeb[i+3] = f2bf(v.w);
  } else if (blk < 9856){
    int r = blk - 9344;
    for (int i = tid; i < 2048; i += 256)
      wead[(size_t)r*2048 + i] = f2bf(Wea[(size_t)r*2048 + i]);
  } else {
    int idx = (blk - 9856)*256 + tid;
    int b = idx >> 7, r = idx & 127;
    out[O_SEQOFF + idx] = seqoff[srt[b]*128 + r];
  }
}

// ============ StageB: embedv3 | att1v4 (LDS stride 138) ============
__global__ __launch_bounds__(256) void k_stageB(const u16* __restrict__ patches,
    const u16* __restrict__ wpeb, const float* __restrict__ b_pe,
    const u16* __restrict__ encbf, const u16* __restrict__ wead,
    const float* __restrict__ bea,
    u16* __restrict__ embbf, float* __restrict__ emb0, u16* __restrict__ att1T){
  __shared__ u16 A[64*138];
  int blk = blockIdx.x, tid = threadIdx.x;
  int wv = tid>>6, lane = tid&63, lr = lane&15, lh = lane>>4;
  if (blk < 128){
    int mb = blk >> 2, nb = blk & 3;
    int m0 = mb*64;
    f32x4 acc[4];
    #pragma unroll
    for (int mt = 0; mt < 4; mt++) acc[mt] = (f32x4){0,0,0,0};
    for (int kc = 0; kc < 24; kc++){
      __syncthreads();
      {
        int row = tid>>2, seg = tid&3;
        const u16* src = patches + (size_t)(m0 + row)*3072 + kc*128 + seg*32;
        #pragma unroll
        for (int i = 0; i < 4; i++)
          *(bf16x8*)&A[row*138 + seg*32 + i*8] = *(const bf16x8*)(src + i*8);
      }
      __syncthreads();
      #pragma unroll
      for (int ki = 0; ki < 4; ki++){
        bf16x8 bv = *(const bf16x8*)&wpeb[(size_t)(nb*64 + wv*16 + lr)*3072 + kc*128 + ki*32 + lh*8];
        #pragma unroll
        for (int mt = 0; mt < 4; mt++){
          bf16x8 av = *(const bf16x8*)&A[(mt*16 + lr)*138 + ki*32 + lh*8];
          acc[mt] = MF(av, bv, acc[mt]);
        }
      }
    }
    int n = nb*64 + wv*16 + lr;
    float bias = b_pe[n];
    #pragma unroll
    for (int mt = 0; mt < 4; mt++){
      #pragma unroll
      for (int r = 0; r < 4; r++){
        int t = mt*16 + lh*4 + r;
        float val = acc[mt][r] + bias;
        embbf[(size_t)(m0 + t)*256 + n] = f2bf(val);
        if (t == 0) emb0[mb*256 + n] = val;
      }
    }
  } else {
    int ab = blk - 128;
    int mb = ab >> 2, nb = ab & 3;
    int m0 = mb*64;
    f32x4 acc[4][2];
    #pragma unroll
    for (int mt = 0; mt < 4; mt++){ acc[mt][0] = (f32x4){0,0,0,0}; acc[mt][1] = (f32x4){0,0,0,0}; }
    for (int kc = 0; kc < 16; kc++){
      __syncthreads();
      {
        int row = tid>>2, seg = tid&3;
        const u16* src = encbf + (size_t)(m0 + row)*2048 + kc*128 + seg*32;
        #pragma unroll
        for (int i = 0; i < 4; i++)
          *(bf16x8*)&A[row*138 + seg*32 + i*8] = *(const bf16x8*)(src + i*8);
      }
      __syncthreads();
      #pragma unroll
      for (int ki = 0; ki < 4; ki++){
        bf16x8 av[4];
        #pragma unroll
        for (int mt = 0; mt < 4; mt++)
          av[mt] = *(const bf16x8*)&A[(mt*16 + lr)*138 + ki*32 + lh*8];
        #pragma unroll
        for (int nt = 0; nt < 2; nt++){
          const u16* wp = wead + (size_t)(nb*128 + wv*32 + nt*16 + lr)*2048 + kc*128 + ki*32 + lh*8;
          bf16x8 bv = *(const bf16x8*)wp;
          #pragma unroll
          for (int mt = 0; mt < 4; mt++) acc[mt][nt] = MF(av[mt], bv, acc[mt][nt]);
        }
      }
    }
    #pragma unroll
    for (int nt = 0; nt < 2; nt++){
      int n = nb*128 + wv*32 + nt*16 + lr;
      float bias = bea[n];
      #pragma unroll
      for (int mt = 0; mt < 4; mt++){
        #pragma unroll
        for (int r = 0; r < 4; r++){
          int m = m0 + mt*16 + lh*4 + r;
          int bb = m / 196, pp = m - bb*196;
          att1T[((size_t)bb*512 + n)*208 + pp] = f2bf(acc[mt][nt][r] + bias);
        }
      }
    }
  }
}

// ============ StageC: W_ih->WIH2/WIHE | WAP | bcomb | initv3 ============
__global__ __launch_bounds__(256) void k_stageC(const float* __restrict__ Wih,
    const float* __restrict__ Whh, const float* __restrict__ Wdec,
    const float* __restrict__ Wfb, const float* __restrict__ Wfc,
    const float* __restrict__ Wstop, const float* __restrict__ bih,
    const float* __restrict__ bhh,
    const float* __restrict__ encm, const float* __restrict__ emb0,
    const float* __restrict__ Wh, const float* __restrict__ Wc,
    u16* __restrict__ WIH2, u16* __restrict__ WIHE, u16* __restrict__ WAP,
    float* __restrict__ bcomb, float* __restrict__ part){
  int blk = blockIdx.x, tid = threadIdx.x;
  if (blk < 2048){
    int r = blk, jp = (r & 511)*4 + (r >> 9);
    for (int i = tid; i < 2304; i += 256){
      u16 v = f2bf(Wih[(size_t)r*2304 + i]);
      if (i < 2048) WIH2[(size_t)jp*2048 + i] = v;
      else          WIHE[(size_t)jp*256 + (i - 2048)] = v;
    }
  } else if (blk < 6720){
    int j = blk - 2048;
    const float* src;
    if (j < 512)        src = Wdec + (size_t)j*512;
    else if (j < 2560)  src = Wfb + (size_t)(j-512)*512;
    else if (j < 4608)  src = Whh + (size_t)(j-2560)*512;
    else if (j == 4608) src = Wfc;
    else if (j == 4609) src = Wfc + 512;
    else if (j == 4610) src = Wstop;
    else src = 0;
    for (int i = tid; i < 512; i += 256)
      WAP[(size_t)j*512 + i] = src ? f2bf(src[i]) : (u16)0;
  } else if (blk < 6728){
    int jp = (blk - 6720)*256 + tid;
    int r = (jp & 3)*512 + (jp >> 2);
    bcomb[jp] = bih[r] + bhh[r];
  } else {
    int ib = blk - 6728;
    int kc = ib >> 4, jb = ib & 15;
    int wv = tid>>6, lane = tid&63, lr = lane&15, lh = lane>>4;
    int j = jb*64 + wv*16 + lr;
    const float* wbase = (j < 512) ? (Wh + (size_t)j*XDIM) : (Wc + (size_t)(j-512)*XDIM);
    f32x4 acc0 = {0,0,0,0}, acc1 = {0,0,0,0};
    #pragma unroll 2
    for (int kk = 0; kk < 576; kk += 32){
      int k = kc*576 + kk + lh*8;
      float4 w0 = *(const float4*)(wbase + k);
      float4 w1 = *(const float4*)(wbase + k + 4);
      bf16x8 bv;
      bv[0]=(short)f2bf(w0.x); bv[1]=(short)f2bf(w0.y); bv[2]=(short)f2bf(w0.z); bv[3]=(short)f2bf(w0.w);
      bv[4]=(short)f2bf(w1.x); bv[5]=(short)f2bf(w1.y); bv[6]=(short)f2bf(w1.z); bv[7]=(short)f2bf(w1.w);
      float4 x0, x1, y0, y1;
      if (k < 2048){
        x0 = *(const float4*)(encm + (size_t)lr*2048 + k);
        x1 = *(const float4*)(encm + (size_t)lr*2048 + k + 4);
        y0 = *(const float4*)(encm + (size_t)(16+lr)*2048 + k);
        y1 = *(const float4*)(encm + (size_t)(16+lr)*2048 + k + 4);
      } else {
        int ke = k - 2048;
        x0 = *(const float4*)(emb0 + (size_t)lr*256 + ke);
        x1 = *(const float4*)(emb0 + (size_t)lr*256 + ke + 4);
        y0 = *(const float4*)(emb0 + (size_t)(16+lr)*256 + ke);
        y1 = *(const float4*)(emb0 + (size_t)(16+lr)*256 + ke + 4);
      }
      bf16x8 a0, a1;
      a0[0]=(short)f2bf(x0.x); a0[1]=(short)f2bf(x0.y); a0[2]=(short)f2bf(x0.z); a0[3]=(short)f2bf(x0.w);
      a0[4]=(short)f2bf(x1.x); a0[5]=(short)f2bf(x1.y); a0[6]=(short)f2bf(x1.z); a0[7]=(short)f2bf(x1.w);
      a1[0]=(short)f2bf(y0.x); a1[1]=(short)f2bf(y0.y); a1[2]=(short)f2bf(y0.z); a1[3]=(short)f2bf(y0.w);
      a1[4]=(short)f2bf(y1.x); a1[5]=(short)f2bf(y1.y); a1[6]=(short)f2bf(y1.z); a1[7]=(short)f2bf(y1.w);
      acc0 = MF(a0, bv, acc0);
      acc1 = MF(a1, bv, acc1);
    }
    #pragma unroll
    for (int r = 0; r < 4; ++r){
      int b0 = lh*4 + r, b1 = 16 + b0;
      part[(size_t)(kc*32 + b0)*1024 + j] = acc0[r];
      part[(size_t)(kc*32 + b1)*1024 + j] = acc1[r];
    }
  }
}

// ============ StageD: gemb | initv3r (gemb LDS stride 266) ============
__global__ __launch_bounds__(256) void k_stageD(const u16* __restrict__ embbf,
    const u16* __restrict__ WIHE, const float* __restrict__ part,
    const float* __restrict__ bh, const float* __restrict__ bc,
    u16* __restrict__ gemb, u16* __restrict__ h_bf, float* __restrict__ c){
  __shared__ u16 A[64*266];
  int blk = blockIdx.x, tid = threadIdx.x;
  if (blk < 256){
    int m0 = (blk >> 3)*64, n0 = (blk & 7)*256;
    int wv = tid>>6, lane = tid&63, lr = lane&15, lh = lane>>4;
    {
      int row = tid>>2, seg = tid&3;
      const u16* src = embbf + (size_t)(m0 + row)*256 + seg*64;
      #pragma unroll
      for (int i = 0; i < 8; i++)
        *(bf16x8*)&A[row*266 + seg*64 + i*8] = *(const bf16x8*)(src + i*8);
    }
    __syncthreads();
    f32x4 acc[4][4];
    #pragma unroll
    for (int mt = 0; mt < 4; mt++)
      #pragma unroll
      for (int nt = 0; nt < 4; nt++) acc[mt][nt] = (f32x4){0,0,0,0};
    #pragma unroll
    for (int ki = 0; ki < 8; ki++){
      bf16x8 av[4];
      #pragma unroll
      for (int mt = 0; mt < 4; mt++)
        av[mt] = *(const bf16x8*)&A[(mt*16 + lr)*266 + ki*32 + lh*8];
      #pragma unroll
      for (int nt = 0; nt < 4; nt++){
        bf16x8 bv = *(const bf16x8*)&WIHE[(size_t)(n0 + wv*64 + nt*16 + lr)*256 + ki*32 + lh*8];
        #pragma unroll
        for (int mt = 0; mt < 4; mt++) acc[mt][nt] = MF(av[mt], bv, acc[mt][nt]);
      }
    }
    #pragma unroll
    for (int nt = 0; nt < 4; nt++){
      int n = n0 + wv*64 + nt*16 + lr;
      #pragma unroll
      for (int mt = 0; mt < 4; mt++)
        #pragma unroll
        for (int r = 0; r < 4; r++)
          gemb[(size_t)(m0 + mt*16 + lh*4 + r)*2048 + n] = f2bf(acc[mt][nt][r]);
    }
  } else {
    int idx = (blk - 256)*256 + tid;
    int b = idx >> 10, j = idx & 1023;
    float s = part[(size_t)b*1024 + j] + part[(size_t)(32+b)*1024 + j]
            + part[(size_t)(64+b)*1024 + j] + part[(size_t)(96+b)*1024 + j];
    if (j < 512) h_bf[(size_t)b*512 + j] = f2bf(s + bh[j]);
    else         c[(size_t)b*512 + (j-512)] = s + bc[j-512];
  }
}

// ============ kAB: fused [kA: pA rows 512..4607 + preds] and [kB1] (HL stride 522) ============
__global__ __launch_bounds__(256) void kAB(const u16* __restrict__ h, const u16* __restrict__ WAP,
    float* __restrict__ pA, const u16* __restrict__ att1T,
    const float* __restrict__ bdec, const float* __restrict__ wfull,
    float* __restrict__ scp, const float* __restrict__ bfc, const float* __restrict__ bstop,
    const int* __restrict__ len, float* __restrict__ out, int t){
  int blk = blockIdx.x, tid = threadIdx.x;
  if (t == 64 && blk != 64) return;      // final call: preds block only
  if (blk < 65){
    __shared__ u16 HL[32*522];
    int wv = tid>>6, lane = tid&63, lr = lane&15, lh = lane>>4;
    for (int i = tid; i < 4096; i += 256){
      unsigned long long v = ((const unsigned long long*)h)[i];
      int row = i >> 7, col = (i & 127)*4;
      *(unsigned long long*)&HL[row*522 + col] = v;
    }
    __syncthreads();
    int j0 = 512 + blk*64 + wv*16;
    f32x4 acc0 = {0,0,0,0}, acc1 = {0,0,0,0};
    #pragma unroll 4
    for (int ki = 0; ki < 16; ++ki){
      bf16x8 bv = *(const bf16x8*)&WAP[(size_t)(j0+lr)*512 + ki*32 + lh*8];
      bf16x8 a0 = *(const bf16x8*)&HL[lr*522 + ki*32 + lh*8];
      bf16x8 a1 = *(const bf16x8*)&HL[(16+lr)*522 + ki*32 + lh*8];
      acc0 = MF(a0, bv, acc0);
      acc1 = MF(a1, bv, acc1);
    }
    int j = j0 + lr;
    if (j < 4608){
      #pragma unroll
      for (int r = 0; r < 4; ++r){
        pA[(size_t)(lh*4+r)*4608 + j]    = acc0[r];
        pA[(size_t)(lh*4+r+16)*4608 + j] = acc1[r];
      }
    } else if (j < 4611 && t > 0){
      int jj = j - 4608, tm1 = t - 1;
      #pragma unroll
      for (int r = 0; r < 4; ++r){
        #pragma unroll
        for (int hb = 0; hb < 2; ++hb){
          int b0 = lh*4 + r + hb*16;
          float val = hb ? acc1[r] : acc0[r];
          bool mk = tm1 < len[b0];
          if (jj < 2) out[O_PRED + ((size_t)b0*64 + tm1)*2 + jj] = mk ? val + bfc[jj] : 0.f;
          else        out[O_STOP + (size_t)b0*64 + tm1] =
                        mk ? 1.f/(1.f + expf(-(val + bstop[0]))) : 0.f;
        }
      }
    }
  } else {
    int kb = blk - 65, b = kb >> 3, ac = kb & 7;
    if (t >= len[b]) return;
    __shared__ u16 hL[512];
    __shared__ float a2s[64], wfs[64];
    if (tid < 128)
      ((unsigned long long*)hL)[tid] = ((const unsigned long long*)(h + (size_t)b*512))[tid];
    if (tid < 64) wfs[tid] = wfull[ac*64 + tid];
    __syncthreads();
    {
      int a = tid >> 2, q = tid & 3;
      const u16* wrow = WAP + (size_t)(ac*64 + a)*512 + q*128;
      const u16* hrow = hL + q*128;
      float acc = 0.f;
      #pragma unroll
      for (int i = 0; i < 16; ++i){
        bf16x8 wv8 = *(const bf16x8*)(wrow + i*8);
        bf16x8 hv8 = *(const bf16x8*)(hrow + i*8);
        #pragma unroll
        for (int e = 0; e < 8; ++e) acc += bf2f((u16)hv8[e]) * bf2f((u16)wv8[e]);
      }
      acc += __shfl_xor(acc, 1);
      acc += __shfl_xor(acc, 2);
      if (q == 0) a2s[a] = acc + bdec[ac*64 + a];
    }
    __syncthreads();
    int p = tid;
    if (p < 196){
      const u16* col = att1T + ((size_t)b*512 + ac*64)*208 + p;
      float acc = 0.f;
      #pragma unroll 8
      for (int a = 0; a < 64; ++a)
        acc += fmaxf(bf2f(col[(size_t)a*208]) + a2s[a], 0.f) * wfs[a];
      scp[(size_t)(b*8 + ac)*200 + p] = acc;
    }
  }
}

// ============ kB2: softmax + awe + gate -> xa ; alphas ============
__global__ __launch_bounds__(256) void kB2(const float* __restrict__ scp,
    const float* __restrict__ pA, const u16* __restrict__ encbf,
    const float* __restrict__ bfull, const float* __restrict__ bfb,
    u16* __restrict__ xa, const int* __restrict__ len, float* __restrict__ out, int t){
  int b = blockIdx.x >> 3, dc = blockIdx.x & 7;
  int tid = threadIdx.x, wv = tid>>6, lane = tid&63;
  if (t >= len[b]){
    if (dc == 0 && tid < 196) out[O_ALPHA + ((size_t)b*64 + t)*196 + tid] = 0.f;
    return;
  }
  __shared__ float ev[200], redf[4], bcx[2];
  float s = -1e30f;
  if (tid < 196){
    s = bfull[0];
    #pragma unroll
    for (int q = 0; q < 8; ++q) s += scp[(size_t)(b*8 + q)*200 + tid];
  }
  float m = s;
  #pragma unroll
  for (int o = 32; o; o >>= 1) m = fmaxf(m, __shfl_down(m, o));
  if (lane == 0) redf[wv] = m;
  __syncthreads();
  if (tid == 0) bcx[0] = fmaxf(fmaxf(redf[0],redf[1]), fmaxf(redf[2],redf[3]));
  __syncthreads();
  float e = (tid < 196) ? expf(s - bcx[0]) : 0.f;
  if (tid < 200) ev[tid] = (tid < 196) ? e : 0.f;
  float sm = e;
  #pragma unroll
  for (int o = 32; o; o >>= 1) sm += __shfl_down(sm, o);
  __syncthreads();
  if (lane == 0) redf[wv] = sm;
  __syncthreads();
  if (tid == 0) bcx[1] = redf[0]+redf[1]+redf[2]+redf[3];
  __syncthreads();
  float ssum = bcx[1];
  int d = dc*256 + tid;
  const u16* ep = encbf + (size_t)(b*196)*ENCD + d;
  float q[8];
  #pragma unroll
  for (int j = 0; j < 8; ++j) q[j] = 0.f;
  #pragma unroll 2
  for (int p = 0; p < 192; p += 8){
    #pragma unroll
    for (int j = 0; j < 8; ++j)
      q[j] += ev[p+j]*bf2f(ep[(size_t)(p+j)*ENCD]);
  }
  #pragma unroll
  for (int j = 0; j < 4; ++j)
    q[j] += ev[192+j]*bf2f(ep[(size_t)(192+j)*ENCD]);
  float awe = (((q[0]+q[1])+(q[2]+q[3])) + ((q[4]+q[5])+(q[6]+q[7]))) / ssum;
  float gp = pA[(size_t)b*4608 + 512 + d] + bfb[d];
  float gate = 1.f/(1.f + expf(-gp));
  xa[(size_t)b*2048 + d] = f2bf(gate * awe);
  if (dc == 0 && tid < 196) out[O_ALPHA + ((size_t)b*64 + t)*196 + tid] = ev[tid]/ssum;
}

// ============ kC: gates GEMM (8-wave K-split) + LSTM fused ============
__global__ __launch_bounds__(512) void kC(const u16* __restrict__ xa,
    const u16* __restrict__ hc, u16* __restrict__ hn, float* __restrict__ c,
    const u16* __restrict__ WIH2, const float* __restrict__ pA,
    const float* __restrict__ bcomb, const u16* __restrict__ gemb,
    const int* __restrict__ len, int t){
  int tid = threadIdx.x, wv = tid>>6, lane = tid&63, lr = lane&15, lh = lane>>4;
  int jp0 = blockIdx.x*16;
  __shared__ float red[8*512];
  f32x4 acc0 = {0,0,0,0}, acc1 = {0,0,0,0};
  #pragma unroll
  for (int ks = 0; ks < 8; ++ks){
    int k = wv*256 + ks*32;
    bf16x8 a0 = *(const bf16x8*)&xa[(size_t)lr*2048 + k + lh*8];
    bf16x8 a1 = *(const bf16x8*)&xa[(size_t)(16+lr)*2048 + k + lh*8];
    bf16x8 bv = *(const bf16x8*)&WIH2[(size_t)(jp0+lr)*2048 + k + lh*8];
    acc0 = MF(a0, bv, acc0);
    acc1 = MF(a1, bv, acc1);
  }
  #pragma unroll
  for (int r = 0; r < 4; ++r){
    red[wv*512 + ((lh*4+r) << 4) + lr]    = acc0[r];
    red[wv*512 + ((16+lh*4+r) << 4) + lr] = acc1[r];
  }
  __syncthreads();
  {
    int b = tid >> 4, jl = tid & 15, e = jl & 3;
    int jp = jp0 + jl, u = jp >> 2;
    float g = 0.f;
    #pragma unroll
    for (int w = 0; w < 8; ++w) g += red[w*512 + tid];
    g += bcomb[jp] + bf2f(gemb[((size_t)b*64 + t)*2048 + jp])
       + pA[(size_t)b*4608 + 2560 + e*512 + u];
    float sv = (e == 2) ? tanhf(g) : 1.f/(1.f + expf(-g));
    float vb = __shfl_xor(sv, 1), vc = __shfl_xor(sv, 2), vd = __shfl_xor(vb, 2);
    float i_s = (e==0)?sv:(e==1)?vb:(e==2)?vc:vd;
    float f_s = (e==1)?sv:(e==0)?vb:(e==3)?vc:vd;
    float g_t = (e==2)?sv:(e==3)?vb:(e==0)?vc:vd;
    float o_s = (e==3)?sv:(e==2)?vb:(e==1)?vc:vd;
    float cold = c[(size_t)b*512 + u];
    float hold = bf2f(hc[(size_t)b*512 + u]);
    bool mk = t < len[b];
    float cn = mk ? (f_s*cold + i_s*g_t) : cold;
    float hv = mk ? (o_s * tanhf(cn)) : hold;
    if (e == 0){
      c[(size_t)b*512 + u] = cn;
      hn[(size_t)b*512 + u] = f2bf(hv);
    }
  }
}

// ================= host launcher =================
extern "C" void kernel_launch(void* const* d_in, const int* in_sizes, int n_in,
                              void* d_out, int out_size, void* d_ws, size_t ws_size,
                              hipStream_t stream){
  (void)in_sizes; (void)n_in; (void)out_size; (void)ws_size;
  const float* enc_out   = (const float*)d_in[0];
  const float* imgs      = (const float*)d_in[1];
  const int*   seq       = (const int*)d_in[2];
  const float* seqoff    = (const float*)d_in[3];
  const int*   caplen    = (const int*)d_in[4];
  const float* W_pe      = (const float*)d_in[5];
  const float* b_pe      = (const float*)d_in[6];
  const float* W_enc_att = (const float*)d_in[7];
  const float* b_enc_att = (const float*)d_in[8];
  const float* W_dec_att = (const float*)d_in[9];
  const float* b_dec_att = (const float*)d_in[10];
  const float* w_full    = (const float*)d_in[11];
  const float* b_full    = (const float*)d_in[12];
  const float* W_init_h  = (const float*)d_in[13];
  const float* b_init_h  = (const float*)d_in[14];
  const float* W_init_c  = (const float*)d_in[15];
  const float* b_init_c  = (const float*)d_in[16];
  const float* W_fb      = (const float*)d_in[17];
  const float* b_fb      = (const float*)d_in[18];
  const float* W_ih      = (const float*)d_in[19];
  const float* b_ih      = (const float*)d_in[20];
  const float* W_hh      = (const float*)d_in[21];
  const float* b_hh      = (const float*)d_in[22];
  const float* W_fc      = (const float*)d_in[23];
  const float* b_fc      = (const float*)d_in[24];
  const float* W_stop    = (const float*)d_in[25];
  const float* b_stop    = (const float*)d_in[26];

  float* out = (float*)d_out;
  float* ws  = (float*)d_ws;
  int*   wsi = (int*)d_ws;
  u16*   us  = (u16*)d_ws;

  u16* H[2] = { us + US_H0, us + US_H1 };

  k_prep<<<1, 64, 0, stream>>>(caplen, wsi + WS_SORT, wsi + WS_LEN, out);
  k_stageA<<<9872, 256, 0, stream>>>(enc_out, imgs, seq, W_pe, W_enc_att, seqoff,
                                     wsi + WS_SORT,
                                     us + US_ENC, ws + WS_ENCM, us + US_PATCH,
                                     us + US_WPEB, us + US_WEA, out);
  k_stageB<<<520, 256, 0, stream>>>(us + US_PATCH, us + US_WPEB, b_pe,
                                    us + US_ENC, us + US_WEA, b_enc_att,
                                    us + US_EMBBF, ws + WS_EMB0, us + US_ATT1T);
  k_stageC<<<6792, 256, 0, stream>>>(W_ih, W_hh, W_dec_att, W_fb, W_fc, W_stop,
                                     b_ih, b_hh,
                                     ws + WS_ENCM, ws + WS_EMB0, W_init_h, W_init_c,
                                     us + US_WIH2, us + US_WIHE, us + US_WAP,
                                     ws + WS_BCOMB, ws + WS_PA);
  k_stageD<<<384, 256, 0, stream>>>(us + US_EMBBF, us + US_WIHE, ws + WS_PA,
                                    b_init_h, b_init_c,
                                    us + US_GEMB, H[0], ws + WS_C);

  for (int t = 0; t < Tn; ++t){
    kAB<<<321, 256, 0, stream>>>(H[t & 1], us + US_WAP, ws + WS_PA, us + US_ATT1T,
                                 b_dec_att, w_full, ws + WS_SCP, b_fc, b_stop,
                                 wsi + WS_LEN, out, t);
    kB2<<<256, 256, 0, stream>>>(ws + WS_SCP, ws + WS_PA, us + US_ENC, b_full, b_fb,
                                 us + US_XA, wsi + WS_LEN, out, t);
    kC<<<128, 512, 0, stream>>>(us + US_XA, H[t & 1], H[(t + 1) & 1], ws + WS_C,
                                us + US_WIH2, ws + WS_PA, ws + WS_BCOMB, us + US_GEMB,
                                wsi + WS_LEN, t);
  }
  kAB<<<65, 256, 0, stream>>>(H[0], us + US_WAP, ws + WS_PA, us + US_ATT1T,
                              b_dec_att, w_full, ws + WS_SCP, b_fc, b_stop,
                              wsi + WS_LEN, out, 64);
}